// Round 5
// baseline (300.435 us; speedup 1.0000x reference)
//
#include <hip/hip_runtime.h>
#include <hip/hip_cooperative_groups.h>
#include <hip/hip_fp16.h>
#include <math.h>

namespace cg = cooperative_groups;

#define NUM_MOVABLE 1000000
#define NUM_FILLER  200000
#define NUM_NODES   1200000
#define NBX 512
#define NBY 512
#define THREADS 256
#define BLOCKS 1024
#define TOTT (THREADS * BLOCKS)   // 262144 == NBX*NBY, one thread per bin

static constexpr float BSX = 1000.0f / 512.0f;   // bin size, exact (1.953125)
static constexpr float TOTAL_PLACE_AREA = 1000000.0f;
static constexpr float TOTAL_WHITESPACE = 500000.0f;
static constexpr float AREA_STOP  = 0.01f;
static constexpr float ROUTE_STOP = 0.01f;
static constexpr float PIN_STOP   = 0.05f;

// 2x2 neighborhood of both maps at (bx,by), fp16-packed: one 16B gather/node.
struct alignas(16) Quad { __half2 r0; __half2 r1; __half2 p0; __half2 p1; };

__device__ __forceinline__ float route_val(const float* m, int idx) {
    return fminf(fmaxf(powf(m[idx], 2.5f), 0.5f), 2.0f);
}
__device__ __forceinline__ float pin_val(const float* m, int idx) {
    return fminf(fmaxf(m[idx], (float)(1.0 / 2.5)), 2.5f);
}

__global__ __launch_bounds__(THREADS, 4) void fused_kernel(
    const float* __restrict__ pos,
    const float* __restrict__ nsx,
    const float* __restrict__ nsy,
    const float* __restrict__ route,
    const float* __restrict__ pin,
    Quad* __restrict__ qmap,
    float4* __restrict__ p4,       // per-block partials (old,inc,r_ex,p_ex)
    float* __restrict__ pf,        // per-block filler-area partial
    float* __restrict__ out)
{
    cg::grid_group grid = cg::this_grid();
    const int tid = blockIdx.x * THREADS + threadIdx.x;   // 0..262143

    // ---------------- phase 0: build fp16 quad map (one bin per thread)
    {
        int bx = tid >> 9, by = tid & 511;
        int bx1 = min(bx + 1, NBX - 1), by1 = min(by + 1, NBY - 1);
        int i00 = bx * NBY + by,  i01 = bx * NBY + by1;
        int i10 = bx1 * NBY + by, i11 = bx1 * NBY + by1;
        Quad q;
        q.r0 = __halves2half2(__float2half(route_val(route, i00)),
                              __float2half(route_val(route, i01)));
        q.r1 = __halves2half2(__float2half(route_val(route, i10)),
                              __float2half(route_val(route, i11)));
        q.p0 = __halves2half2(__float2half(pin_val(pin, i00)),
                              __float2half(pin_val(pin, i01)));
        q.p1 = __halves2half2(__float2half(pin_val(pin, i10)),
                              __float2half(pin_val(pin, i11)));
        qmap[tid] = q;
    }

    // ---------------- register-cache node data (independent of qmap)
    const bool isf = tid < NUM_FILLER;
    float fpx = 0.f, fpy = 0.f, fsx = 0.f, fsy = 0.f, sf = 0.f;
    if (isf) {
        int j = NUM_MOVABLE + tid;
        fsx = nsx[j]; fsy = nsy[j];
        fpx = pos[j]; fpy = pos[NUM_NODES + j];
        sf = fsx * fsy;
    }
    float mpx[4], mpy[4], msx[4], msy[4];
    #pragma unroll
    for (int k = 0; k < 4; ++k) {
        int i = tid + k * TOTT;
        int ii = (i < NUM_MOVABLE) ? i : 0;
        mpx[k] = pos[ii]; mpy[k] = pos[NUM_NODES + ii];
        msx[k] = nsx[ii]; msy[k] = nsy[ii];
    }

    grid.sync();   // qmap now visible to all blocks

    // ---------------- phase A: gather + per-node increment (kept in regs)
    // node size <= 1.2 < bin 1.953125  =>  2x2 window only.
    float mai[4];
    float s_old = 0.f, s_inc = 0.f, s_r = 0.f, s_p = 0.f;
    #pragma unroll
    for (int k = 0; k < 4; ++k) {
        bool valid = (tid + k * TOTT) < NUM_MOVABLE;
        float px = mpx[k], py = mpy[k], sx = msx[k], sy = msy[k];
        float hix = px + sx, hiy = py + sy;
        int b0x = (int)floorf(px / BSX);
        int b0y = (int)floorf(py / BSX);
        float ex = (float)(b0x + 1) * BSX;
        float ey = (float)(b0y + 1) * BSX;
        float wx0 = fminf(hix, ex) - px;
        float wx1 = fmaxf(hix - ex, 0.0f);
        float wy0 = fminf(hiy, ey) - py;
        float wy1 = fmaxf(hiy - ey, 0.0f);

        Quad q = qmap[b0x * NBY + b0y];      // one 16B aligned gather
        float2 r0 = __half22float2(q.r0), r1 = __half22float2(q.r1);
        float2 p0 = __half22float2(q.p0), p1 = __half22float2(q.p1);

        float r = wx0 * (wy0 * r0.x + wy1 * r0.y) + wx1 * (wy0 * r1.x + wy1 * r1.y);
        float p = wx0 * (wy0 * p0.x + wy1 * p0.y) + wx1 * (wy0 * p1.x + wy1 * p1.y);

        float old_a = sx * sy;
        float ai = fmaxf(fmaxf(r, p) - old_a, 0.0f);
        mai[k] = ai;
        if (valid) {
            s_old += old_a;
            s_inc += ai;
            s_r += fmaxf(r - old_a, 0.0f);
            s_p += fmaxf(p - old_a, 0.0f);
        }
    }

    // ---------------- block reduce 5 values -> stores (no atomics)
    __shared__ float red[4][5];
    __shared__ float der[4];
    {
        float v0 = s_old, v1 = s_inc, v2 = s_r, v3 = s_p, v4 = sf;
        #pragma unroll
        for (int o = 32; o >= 1; o >>= 1) {
            v0 += __shfl_down(v0, o, 64);
            v1 += __shfl_down(v1, o, 64);
            v2 += __shfl_down(v2, o, 64);
            v3 += __shfl_down(v3, o, 64);
            v4 += __shfl_down(v4, o, 64);
        }
        int wid = threadIdx.x >> 6, lid = threadIdx.x & 63;
        if (lid == 0) { red[wid][0] = v0; red[wid][1] = v1; red[wid][2] = v2;
                        red[wid][3] = v3; red[wid][4] = v4; }
        __syncthreads();
        if (threadIdx.x == 0) {
            float a0 = 0.f, a1 = 0.f, a2 = 0.f, a3 = 0.f, a4 = 0.f;
            for (int w = 0; w < 4; ++w) {
                a0 += red[w][0]; a1 += red[w][1]; a2 += red[w][2];
                a3 += red[w][3]; a4 += red[w][4];
            }
            p4[blockIdx.x] = make_float4(a0, a1, a2, a3);
            pf[blockIdx.x] = a4;
        }
    }

    grid.sync();   // all partials visible

    // ---------------- phase B: every block folds all partials (L2-cheap)
    {
        float t0 = 0.f, t1 = 0.f, t2 = 0.f, t3 = 0.f, t4 = 0.f;
        #pragma unroll
        for (int k = 0; k < BLOCKS / THREADS; ++k) {
            int b = threadIdx.x + k * THREADS;
            float4 v = p4[b];
            t0 += v.x; t1 += v.y; t2 += v.z; t3 += v.w;
            t4 += pf[b];
        }
        #pragma unroll
        for (int o = 32; o >= 1; o >>= 1) {
            t0 += __shfl_down(t0, o, 64);
            t1 += __shfl_down(t1, o, 64);
            t2 += __shfl_down(t2, o, 64);
            t3 += __shfl_down(t3, o, 64);
            t4 += __shfl_down(t4, o, 64);
        }
        int wid = threadIdx.x >> 6, lid = threadIdx.x & 63;
        __syncthreads();   // red[] reuse hazard
        if (lid == 0) { red[wid][0] = t0; red[wid][1] = t1; red[wid][2] = t2;
                        red[wid][3] = t3; red[wid][4] = t4; }
        __syncthreads();
        if (threadIdx.x == 0) {
            float old_sum = 0.f, inc_sum = 0.f, route_ex = 0.f, pin_ex = 0.f, filler_sum = 0.f;
            for (int w = 0; w < 4; ++w) {
                old_sum += red[w][0]; inc_sum += red[w][1]; route_ex += red[w][2];
                pin_ex += red[w][3]; filler_sum += red[w][4];
            }
            float budget = fminf(0.1f * TOTAL_WHITESPACE, TOTAL_PLACE_AREA - old_sum);
            float raw = budget / inc_sum;
            float scale = fminf(fmaxf(raw, 0.0f), 1.0f);
            float scale_eff = (raw <= 0.0f) ? 0.0f : scale;
            float inc_eff = (raw <= 0.0f) ? 0.0f : inc_sum * scale;
            float new_sum = old_sum + inc_eff;
            float area_ratio = inc_eff / old_sum;
            bool route_flag = (route_ex / old_sum) > ROUTE_STOP;
            bool pin_flag = (pin_ex / old_sum) > PIN_STOP;
            bool adjust = (area_ratio > AREA_STOP) && (route_flag || pin_flag);
            bool fcond = adjust && (new_sum + filler_sum > TOTAL_PLACE_AREA);
            float fratio = sqrtf(fmaxf(TOTAL_PLACE_AREA - new_sum, 0.0f) / filler_sum);
            der[0] = adjust ? 1.0f : 0.0f;
            der[1] = scale_eff;
            der[2] = fcond ? 1.0f : 0.0f;
            der[3] = fratio;
        }
        __syncthreads();
    }
    const float adjust = der[0], scale_eff = der[1];
    const float fcond = der[2], fratio = der[3];

    // ---------------- phase C: apply from registers, write out
    #pragma unroll
    for (int k = 0; k < 4; ++k) {
        int i = tid + k * TOTT;
        if (i < NUM_MOVABLE) {
            float px = mpx[k], py = mpy[k], sx = msx[k], sy = msy[k];
            float nx = sx, ny = sy, opx = px, opy = py;
            if (adjust > 0.5f) {
                float old_a = sx * sy;
                float na = old_a + mai[k] * scale_eff;
                float mr = sqrtf(na / old_a);
                nx = sx * mr; ny = sy * mr;
                opx = px + 0.5f * (sx - nx);
                opy = py + 0.5f * (sy - ny);
            }
            out[i] = opx;
            out[NUM_NODES + i] = opy;
            out[2 * NUM_NODES + i] = nx;
            out[3 * NUM_NODES + i] = ny;
        }
    }
    if (isf) {
        int j = NUM_MOVABLE + tid;
        float nx = fsx, ny = fsy, opx = fpx, opy = fpy;
        if (fcond > 0.5f) {
            nx = fsx * fratio; ny = fsy * fratio;
            opx = fpx + 0.5f * (fsx - nx);
            opy = fpy + 0.5f * (fsy - ny);
        }
        out[j] = opx;
        out[NUM_NODES + j] = opy;
        out[2 * NUM_NODES + j] = nx;
        out[3 * NUM_NODES + j] = ny;
    }
}

// ---------------------------------------------------------------- launch
extern "C" void kernel_launch(void* const* d_in, const int* in_sizes, int n_in,
                              void* d_out, int out_size, void* d_ws, size_t ws_size,
                              hipStream_t stream) {
    const float* pos       = (const float*)d_in[0];
    const float* node_sx   = (const float*)d_in[1];
    const float* node_sy   = (const float*)d_in[2];
    // d_in[3] pin_offset_x, d_in[4] pin_offset_y, d_in[5] target_density: unused
    const float* route_map = (const float*)d_in[6];
    const float* pin_map   = (const float*)d_in[7];
    float* out = (float*)d_out;

    char*   ws   = (char*)d_ws;
    Quad*   qmap = (Quad*)ws;                         // 4 MB quad map
    float4* p4   = (float4*)(ws + sizeof(Quad) * NBX * NBY);
    float*  pf   = (float*)(p4 + BLOCKS);

    void* args[] = { (void*)&pos, (void*)&node_sx, (void*)&node_sy,
                     (void*)&route_map, (void*)&pin_map,
                     (void*)&qmap, (void*)&p4, (void*)&pf, (void*)&out };
    hipLaunchCooperativeKernel((void*)fused_kernel, dim3(BLOCKS), dim3(THREADS),
                               args, 0, stream);
}

// Round 6
// 126.348 us; speedup vs baseline: 2.3778x; 2.3778x over previous
//
#include <hip/hip_runtime.h>
#include <math.h>

#define NUM_MOVABLE 1000000
#define NUM_FILLER  200000
#define NUM_NODES   1200000
#define NBX 512
#define NBY 512
#define THREADS 256
#define NGROUPS 300000          // NUM_NODES / 4 (float4 groups)
#define MGROUPS 250000          // NUM_MOVABLE / 4 (boundary never straddled)
#define P1_BLOCKS ((NGROUPS + THREADS - 1) / THREADS)   // 1172

static constexpr float BSX = 1000.0f / 512.0f;   // 1.953125, exact in fp32
static constexpr float TOTAL_PLACE_AREA = 1000000.0f;
static constexpr float TOTAL_WHITESPACE = 500000.0f;
static constexpr float AREA_STOP  = 0.01f;
static constexpr float ROUTE_STOP = 0.01f;
static constexpr float PIN_STOP   = 0.05f;

__device__ __forceinline__ float route_val(float x) {
    return fminf(fmaxf(powf(x, 2.5f), 0.5f), 2.0f);
}
__device__ __forceinline__ float pin_val(float x) {
    return fminf(fmaxf(x, 0.4f), 2.5f);
}

// block-reduce 5 values -> one float4 + one float store (NO atomics)
__device__ __forceinline__ void block_reduce_store5(float v0, float v1, float v2,
                                                    float v3, float v4,
                                                    float4* d4, float* df) {
    __shared__ float red[4][5];
    #pragma unroll
    for (int o = 32; o >= 1; o >>= 1) {
        v0 += __shfl_down(v0, o, 64);
        v1 += __shfl_down(v1, o, 64);
        v2 += __shfl_down(v2, o, 64);
        v3 += __shfl_down(v3, o, 64);
        v4 += __shfl_down(v4, o, 64);
    }
    int wid = threadIdx.x >> 6, lid = threadIdx.x & 63;
    if (lid == 0) { red[wid][0] = v0; red[wid][1] = v1; red[wid][2] = v2;
                    red[wid][3] = v3; red[wid][4] = v4; }
    __syncthreads();
    if (threadIdx.x == 0) {
        float a0 = 0.f, a1 = 0.f, a2 = 0.f, a3 = 0.f, a4 = 0.f;
        for (int w = 0; w < 4; ++w) {
            a0 += red[w][0]; a1 += red[w][1]; a2 += red[w][2];
            a3 += red[w][3]; a4 += red[w][4];
        }
        *d4 = make_float4(a0, a1, a2, a3);
        *df = a4;
    }
}

// --------- pass 1: direct 2x2 gather from raw maps + filler sum + partials
// node size <= 1.2 < bin 1.953125  =>  only a 2x2 bin window overlaps.
__global__ void pass1_kernel(const float* __restrict__ pos,
                             const float* __restrict__ nsx,
                             const float* __restrict__ nsy,
                             const float* __restrict__ route,
                             const float* __restrict__ pin,
                             float* __restrict__ inc,
                             float4* __restrict__ part4,
                             float* __restrict__ partf) {
    int t = blockIdx.x * THREADS + threadIdx.x;
    float s_old = 0.f, s_inc = 0.f, s_r = 0.f, s_p = 0.f, sf = 0.f;

    if (t < MGROUPS) {
        float4 px4 = ((const float4*)pos)[t];
        float4 py4 = ((const float4*)(pos + NUM_NODES))[t];
        float4 sx4 = ((const float4*)nsx)[t];
        float4 sy4 = ((const float4*)nsy)[t];
        float ai4[4];
        #pragma unroll
        for (int j = 0; j < 4; ++j) {
            float px = (&px4.x)[j], py = (&py4.x)[j];
            float sx = (&sx4.x)[j], sy = (&sy4.x)[j];
            float hix = px + sx, hiy = py + sy;
            int b0x = (int)floorf(px / BSX);      // same fp32 div as reference
            int b0y = (int)floorf(py / BSX);
            float ex = (float)(b0x + 1) * BSX;    // exact: (b+1)*125/64 < 2^24
            float ey = (float)(b0y + 1) * BSX;
            float wx0 = fminf(hix, ex) - px;
            float wx1 = fmaxf(hix - ex, 0.0f);    // 0 whenever b0x+1 == NBX
            float wy0 = fminf(hiy, ey) - py;
            float wy1 = fmaxf(hiy - ey, 0.0f);
            int bx1 = min(b0x + 1, NBX - 1);      // clamped index, weight=0 there
            int by1 = min(b0y + 1, NBY - 1);
            int r0 = b0x * NBY, r1 = bx1 * NBY;

            float r00 = route_val(route[r0 + b0y]);
            float r01 = route_val(route[r0 + by1]);
            float r10 = route_val(route[r1 + b0y]);
            float r11 = route_val(route[r1 + by1]);
            float p00 = pin_val(pin[r0 + b0y]);
            float p01 = pin_val(pin[r0 + by1]);
            float p10 = pin_val(pin[r1 + b0y]);
            float p11 = pin_val(pin[r1 + by1]);

            float r = wx0 * (wy0 * r00 + wy1 * r01) + wx1 * (wy0 * r10 + wy1 * r11);
            float p = wx0 * (wy0 * p00 + wy1 * p01) + wx1 * (wy0 * p10 + wy1 * p11);

            float old_a = sx * sy;
            float ai = fmaxf(fmaxf(r, p) - old_a, 0.0f);
            ai4[j] = ai;
            s_old += old_a;
            s_inc += ai;
            s_r += fmaxf(r - old_a, 0.0f);
            s_p += fmaxf(p - old_a, 0.0f);
        }
        ((float4*)inc)[t] = make_float4(ai4[0], ai4[1], ai4[2], ai4[3]);
    } else if (t < NGROUPS) {
        float4 sx4 = ((const float4*)nsx)[t];
        float4 sy4 = ((const float4*)nsy)[t];
        sf = sx4.x * sy4.x + sx4.y * sy4.y + sx4.z * sy4.z + sx4.w * sy4.w;
    }
    block_reduce_store5(s_old, s_inc, s_r, s_p, sf,
                        part4 + blockIdx.x, partf + blockIdx.x);
}

// --------- apply: every block folds the 1172 partials (L2 broadcast-cheap),
//           computes decision scalars, then applies its 4-node groups.
__global__ void apply_kernel(const float* __restrict__ pos,
                             const float* __restrict__ nsx,
                             const float* __restrict__ nsy,
                             const float* __restrict__ inc,
                             const float4* __restrict__ part4,
                             const float* __restrict__ partf,
                             float* __restrict__ out) {
    __shared__ float red[4][5];
    __shared__ float der[4];
    {
        float t0 = 0.f, t1 = 0.f, t2 = 0.f, t3 = 0.f, t4 = 0.f;
        for (int b = threadIdx.x; b < P1_BLOCKS; b += THREADS) {
            float4 v = part4[b];
            t0 += v.x; t1 += v.y; t2 += v.z; t3 += v.w;
            t4 += partf[b];
        }
        #pragma unroll
        for (int o = 32; o >= 1; o >>= 1) {
            t0 += __shfl_down(t0, o, 64);
            t1 += __shfl_down(t1, o, 64);
            t2 += __shfl_down(t2, o, 64);
            t3 += __shfl_down(t3, o, 64);
            t4 += __shfl_down(t4, o, 64);
        }
        int wid = threadIdx.x >> 6, lid = threadIdx.x & 63;
        if (lid == 0) { red[wid][0] = t0; red[wid][1] = t1; red[wid][2] = t2;
                        red[wid][3] = t3; red[wid][4] = t4; }
        __syncthreads();
        if (threadIdx.x == 0) {
            float old_sum = 0.f, inc_sum = 0.f, route_ex = 0.f, pin_ex = 0.f, filler_sum = 0.f;
            for (int w = 0; w < 4; ++w) {
                old_sum += red[w][0]; inc_sum += red[w][1]; route_ex += red[w][2];
                pin_ex += red[w][3]; filler_sum += red[w][4];
            }
            float budget = fminf(0.1f * TOTAL_WHITESPACE, TOTAL_PLACE_AREA - old_sum);
            float raw = budget / inc_sum;
            float scale = fminf(fmaxf(raw, 0.0f), 1.0f);
            float scale_eff = (raw <= 0.0f) ? 0.0f : scale;
            float inc_eff = (raw <= 0.0f) ? 0.0f : inc_sum * scale;
            float new_sum = old_sum + inc_eff;
            float area_ratio = inc_eff / old_sum;
            bool route_flag = (route_ex / old_sum) > ROUTE_STOP;
            bool pin_flag = (pin_ex / old_sum) > PIN_STOP;
            bool adjust = (area_ratio > AREA_STOP) && (route_flag || pin_flag);
            bool fcond = adjust && (new_sum + filler_sum > TOTAL_PLACE_AREA);
            float fratio = sqrtf(fmaxf(TOTAL_PLACE_AREA - new_sum, 0.0f) / filler_sum);
            der[0] = adjust ? 1.0f : 0.0f;
            der[1] = scale_eff;
            der[2] = fcond ? 1.0f : 0.0f;
            der[3] = fratio;
        }
        __syncthreads();
    }
    const float adjust = der[0], scale_eff = der[1];
    const float fcond = der[2], fratio = der[3];

    int t = blockIdx.x * THREADS + threadIdx.x;
    if (t >= NGROUPS) return;

    float4 px4 = ((const float4*)pos)[t];
    float4 py4 = ((const float4*)(pos + NUM_NODES))[t];
    float4 sx4 = ((const float4*)nsx)[t];
    float4 sy4 = ((const float4*)nsy)[t];
    float nx[4], ny[4], opx[4], opy[4];

    if (t < MGROUPS) {
        float4 ai4 = ((const float4*)inc)[t];
        #pragma unroll
        for (int j = 0; j < 4; ++j) {
            float px = (&px4.x)[j], py = (&py4.x)[j];
            float sx = (&sx4.x)[j], sy = (&sy4.x)[j];
            nx[j] = sx; ny[j] = sy; opx[j] = px; opy[j] = py;
            if (adjust > 0.5f) {
                float old_a = sx * sy;
                float na = old_a + (&ai4.x)[j] * scale_eff;
                float mr = sqrtf(na / old_a);
                nx[j] = sx * mr; ny[j] = sy * mr;
                opx[j] = px + 0.5f * (sx - nx[j]);
                opy[j] = py + 0.5f * (sy - ny[j]);
            }
        }
    } else {
        #pragma unroll
        for (int j = 0; j < 4; ++j) {
            float px = (&px4.x)[j], py = (&py4.x)[j];
            float sx = (&sx4.x)[j], sy = (&sy4.x)[j];
            nx[j] = sx; ny[j] = sy; opx[j] = px; opy[j] = py;
            if (fcond > 0.5f) {
                nx[j] = sx * fratio; ny[j] = sy * fratio;
                opx[j] = px + 0.5f * (sx - nx[j]);
                opy[j] = py + 0.5f * (sy - ny[j]);
            }
        }
    }
    ((float4*)out)[t]                   = make_float4(opx[0], opx[1], opx[2], opx[3]);
    ((float4*)(out + NUM_NODES))[t]     = make_float4(opy[0], opy[1], opy[2], opy[3]);
    ((float4*)(out + 2 * NUM_NODES))[t] = make_float4(nx[0], nx[1], nx[2], nx[3]);
    ((float4*)(out + 3 * NUM_NODES))[t] = make_float4(ny[0], ny[1], ny[2], ny[3]);
}

// ---------------------------------------------------------------- launch
extern "C" void kernel_launch(void* const* d_in, const int* in_sizes, int n_in,
                              void* d_out, int out_size, void* d_ws, size_t ws_size,
                              hipStream_t stream) {
    const float* pos       = (const float*)d_in[0];
    const float* node_sx   = (const float*)d_in[1];
    const float* node_sy   = (const float*)d_in[2];
    // d_in[3] pin_offset_x, d_in[4] pin_offset_y, d_in[5] target_density: unused
    const float* route_map = (const float*)d_in[6];
    const float* pin_map   = (const float*)d_in[7];
    float* out = (float*)d_out;

    float*  ws    = (float*)d_ws;
    float*  inc   = ws;                        // 4 MB per-node increments
    float4* part4 = (float4*)(inc + NUM_MOVABLE);
    float*  partf = (float*)(part4 + P1_BLOCKS);

    hipLaunchKernelGGL(pass1_kernel, dim3(P1_BLOCKS), dim3(THREADS), 0, stream,
                       pos, node_sx, node_sy, route_map, pin_map, inc, part4, partf);
    hipLaunchKernelGGL(apply_kernel, dim3(P1_BLOCKS), dim3(THREADS), 0, stream,
                       pos, node_sx, node_sy, inc, part4, partf, out);
}

// Round 7
// 107.257 us; speedup vs baseline: 2.8011x; 1.1780x over previous
//
#include <hip/hip_runtime.h>
#include <hip/hip_fp16.h>
#include <math.h>

#define NUM_MOVABLE 1000000
#define NUM_FILLER  200000
#define NUM_NODES   1200000
#define NBX 512
#define NBY 512
#define THREADS 256
#define NGROUPS 300000          // NUM_NODES / 4
#define MGROUPS 250000          // NUM_MOVABLE / 4
#define PREP_BLOCKS 1024        // 262144 threads: one per bin
#define P1_BLOCKS ((MGROUPS + THREADS - 1) / THREADS)    // 977
#define AP_BLOCKS ((NGROUPS + THREADS - 1) / THREADS)    // 1172

static constexpr float BSX = 1000.0f / 512.0f;   // 1.953125, exact in fp32
static constexpr float TOTAL_PLACE_AREA = 1000000.0f;
static constexpr float TOTAL_WHITESPACE = 500000.0f;
static constexpr float AREA_STOP  = 0.01f;
static constexpr float ROUTE_STOP = 0.01f;
static constexpr float PIN_STOP   = 0.05f;

// 2x2 neighborhood of both maps at (bx,by), fp16: ONE 16B gather per node.
struct alignas(16) Quad { __half2 r0; __half2 r1; __half2 p0; __half2 p1; };

__device__ __forceinline__ float route_val(const float* m, int idx) {
    return fminf(fmaxf(powf(m[idx], 2.5f), 0.5f), 2.0f);
}
__device__ __forceinline__ float pin_val(const float* m, int idx) {
    return fminf(fmaxf(m[idx], 0.4f), 2.5f);
}

// ---------------- prep: fp16 quad map (powf once per bin) + filler partials
__global__ void prep_kernel(const float* __restrict__ route,
                            const float* __restrict__ pin,
                            const float* __restrict__ nsx,
                            const float* __restrict__ nsy,
                            Quad* __restrict__ qmap,
                            float* __restrict__ pf) {
    int i = blockIdx.x * THREADS + threadIdx.x;   // 0..262143
    {
        int bx = i >> 9, by = i & 511;
        int bx1 = min(bx + 1, NBX - 1), by1 = min(by + 1, NBY - 1);
        int i00 = bx * NBY + by,  i01 = bx * NBY + by1;
        int i10 = bx1 * NBY + by, i11 = bx1 * NBY + by1;
        Quad q;
        q.r0 = __halves2half2(__float2half(route_val(route, i00)),
                              __float2half(route_val(route, i01)));
        q.r1 = __halves2half2(__float2half(route_val(route, i10)),
                              __float2half(route_val(route, i11)));
        q.p0 = __halves2half2(__float2half(pin_val(pin, i00)),
                              __float2half(pin_val(pin, i01)));
        q.p1 = __halves2half2(__float2half(pin_val(pin, i10)),
                              __float2half(pin_val(pin, i11)));
        qmap[i] = q;
    }
    float s = 0.f;
    if (i < NUM_FILLER) {
        int j = NUM_MOVABLE + i;
        s = nsx[j] * nsy[j];
    }
    // block reduce -> single store (no atomics)
    __shared__ float red[4];
    #pragma unroll
    for (int o = 32; o >= 1; o >>= 1) s += __shfl_down(s, o, 64);
    int wid = threadIdx.x >> 6, lid = threadIdx.x & 63;
    if (lid == 0) red[wid] = s;
    __syncthreads();
    if (threadIdx.x == 0)
        pf[blockIdx.x] = red[0] + red[1] + red[2] + red[3];
}

// ---------------- pass 1: 4 movable nodes/thread, one 16B gather each
// node size <= 1.2 < bin 1.953125  =>  only a 2x2 bin window overlaps.
__global__ void pass1_kernel(const float* __restrict__ pos,
                             const float* __restrict__ nsx,
                             const float* __restrict__ nsy,
                             const Quad* __restrict__ qmap,
                             float* __restrict__ inc,
                             float4* __restrict__ part4) {
    int t = blockIdx.x * THREADS + threadIdx.x;
    float s_old = 0.f, s_inc = 0.f, s_r = 0.f, s_p = 0.f;

    if (t < MGROUPS) {
        float4 px4 = ((const float4*)pos)[t];
        float4 py4 = ((const float4*)(pos + NUM_NODES))[t];
        float4 sx4 = ((const float4*)nsx)[t];
        float4 sy4 = ((const float4*)nsy)[t];

        // issue all 4 independent gathers first (ILP for latency hiding)
        Quad q[4];
        float wx0[4], wx1[4], wy0[4], wy1[4];
        #pragma unroll
        for (int j = 0; j < 4; ++j) {
            float px = (&px4.x)[j], py = (&py4.x)[j];
            float sx = (&sx4.x)[j], sy = (&sy4.x)[j];
            float hix = px + sx, hiy = py + sy;
            int b0x = (int)floorf(px / BSX);
            int b0y = (int)floorf(py / BSX);
            float ex = (float)(b0x + 1) * BSX;
            float ey = (float)(b0y + 1) * BSX;
            wx0[j] = fminf(hix, ex) - px;
            wx1[j] = fmaxf(hix - ex, 0.0f);
            wy0[j] = fminf(hiy, ey) - py;
            wy1[j] = fmaxf(hiy - ey, 0.0f);
            q[j] = qmap[b0x * NBY + b0y];
        }
        float ai4[4];
        #pragma unroll
        for (int j = 0; j < 4; ++j) {
            float2 r0 = __half22float2(q[j].r0), r1 = __half22float2(q[j].r1);
            float2 p0 = __half22float2(q[j].p0), p1 = __half22float2(q[j].p1);
            float r = wx0[j] * (wy0[j] * r0.x + wy1[j] * r0.y)
                    + wx1[j] * (wy0[j] * r1.x + wy1[j] * r1.y);
            float p = wx0[j] * (wy0[j] * p0.x + wy1[j] * p0.y)
                    + wx1[j] * (wy0[j] * p1.x + wy1[j] * p1.y);
            float sx = (&sx4.x)[j], sy = (&sy4.x)[j];
            float old_a = sx * sy;
            float ai = fmaxf(fmaxf(r, p) - old_a, 0.0f);
            ai4[j] = ai;
            s_old += old_a;
            s_inc += ai;
            s_r += fmaxf(r - old_a, 0.0f);
            s_p += fmaxf(p - old_a, 0.0f);
        }
        ((float4*)inc)[t] = make_float4(ai4[0], ai4[1], ai4[2], ai4[3]);
    }

    __shared__ float red[4][4];
    #pragma unroll
    for (int o = 32; o >= 1; o >>= 1) {
        s_old += __shfl_down(s_old, o, 64);
        s_inc += __shfl_down(s_inc, o, 64);
        s_r   += __shfl_down(s_r, o, 64);
        s_p   += __shfl_down(s_p, o, 64);
    }
    int wid = threadIdx.x >> 6, lid = threadIdx.x & 63;
    if (lid == 0) { red[wid][0] = s_old; red[wid][1] = s_inc;
                    red[wid][2] = s_r;   red[wid][3] = s_p; }
    __syncthreads();
    if (threadIdx.x == 0) {
        float a0 = 0.f, a1 = 0.f, a2 = 0.f, a3 = 0.f;
        for (int w = 0; w < 4; ++w) {
            a0 += red[w][0]; a1 += red[w][1]; a2 += red[w][2]; a3 += red[w][3];
        }
        part4[blockIdx.x] = make_float4(a0, a1, a2, a3);
    }
}

// ---------------- apply: per-block fold of partials, then streaming apply
__global__ void apply_kernel(const float* __restrict__ pos,
                             const float* __restrict__ nsx,
                             const float* __restrict__ nsy,
                             const float* __restrict__ inc,
                             const float4* __restrict__ part4,
                             const float* __restrict__ pf,
                             float* __restrict__ out) {
    __shared__ float red[4][5];
    __shared__ float der[4];
    {
        float t0 = 0.f, t1 = 0.f, t2 = 0.f, t3 = 0.f, t4 = 0.f;
        for (int b = threadIdx.x; b < P1_BLOCKS; b += THREADS) {
            float4 v = part4[b];
            t0 += v.x; t1 += v.y; t2 += v.z; t3 += v.w;
        }
        for (int b = threadIdx.x; b < PREP_BLOCKS; b += THREADS) t4 += pf[b];
        #pragma unroll
        for (int o = 32; o >= 1; o >>= 1) {
            t0 += __shfl_down(t0, o, 64);
            t1 += __shfl_down(t1, o, 64);
            t2 += __shfl_down(t2, o, 64);
            t3 += __shfl_down(t3, o, 64);
            t4 += __shfl_down(t4, o, 64);
        }
        int wid = threadIdx.x >> 6, lid = threadIdx.x & 63;
        if (lid == 0) { red[wid][0] = t0; red[wid][1] = t1; red[wid][2] = t2;
                        red[wid][3] = t3; red[wid][4] = t4; }
        __syncthreads();
        if (threadIdx.x == 0) {
            float old_sum = 0.f, inc_sum = 0.f, route_ex = 0.f, pin_ex = 0.f, filler_sum = 0.f;
            for (int w = 0; w < 4; ++w) {
                old_sum += red[w][0]; inc_sum += red[w][1]; route_ex += red[w][2];
                pin_ex += red[w][3]; filler_sum += red[w][4];
            }
            float budget = fminf(0.1f * TOTAL_WHITESPACE, TOTAL_PLACE_AREA - old_sum);
            float raw = budget / inc_sum;
            float scale = fminf(fmaxf(raw, 0.0f), 1.0f);
            float scale_eff = (raw <= 0.0f) ? 0.0f : scale;
            float inc_eff = (raw <= 0.0f) ? 0.0f : inc_sum * scale;
            float new_sum = old_sum + inc_eff;
            float area_ratio = inc_eff / old_sum;
            bool route_flag = (route_ex / old_sum) > ROUTE_STOP;
            bool pin_flag = (pin_ex / old_sum) > PIN_STOP;
            bool adjust = (area_ratio > AREA_STOP) && (route_flag || pin_flag);
            bool fcond = adjust && (new_sum + filler_sum > TOTAL_PLACE_AREA);
            float fratio = sqrtf(fmaxf(TOTAL_PLACE_AREA - new_sum, 0.0f) / filler_sum);
            der[0] = adjust ? 1.0f : 0.0f;
            der[1] = scale_eff;
            der[2] = fcond ? 1.0f : 0.0f;
            der[3] = fratio;
        }
        __syncthreads();
    }
    const float adjust = der[0], scale_eff = der[1];
    const float fcond = der[2], fratio = der[3];

    int t = blockIdx.x * THREADS + threadIdx.x;
    if (t >= NGROUPS) return;

    float4 px4 = ((const float4*)pos)[t];
    float4 py4 = ((const float4*)(pos + NUM_NODES))[t];
    float4 sx4 = ((const float4*)nsx)[t];
    float4 sy4 = ((const float4*)nsy)[t];
    float nx[4], ny[4], opx[4], opy[4];

    if (t < MGROUPS) {
        float4 ai4 = ((const float4*)inc)[t];
        #pragma unroll
        for (int j = 0; j < 4; ++j) {
            float px = (&px4.x)[j], py = (&py4.x)[j];
            float sx = (&sx4.x)[j], sy = (&sy4.x)[j];
            nx[j] = sx; ny[j] = sy; opx[j] = px; opy[j] = py;
            if (adjust > 0.5f) {
                float old_a = sx * sy;
                float na = old_a + (&ai4.x)[j] * scale_eff;
                float mr = sqrtf(na / old_a);
                nx[j] = sx * mr; ny[j] = sy * mr;
                opx[j] = px + 0.5f * (sx - nx[j]);
                opy[j] = py + 0.5f * (sy - ny[j]);
            }
        }
    } else {
        #pragma unroll
        for (int j = 0; j < 4; ++j) {
            float px = (&px4.x)[j], py = (&py4.x)[j];
            float sx = (&sx4.x)[j], sy = (&sy4.x)[j];
            nx[j] = sx; ny[j] = sy; opx[j] = px; opy[j] = py;
            if (fcond > 0.5f) {
                nx[j] = sx * fratio; ny[j] = sy * fratio;
                opx[j] = px + 0.5f * (sx - nx[j]);
                opy[j] = py + 0.5f * (sy - ny[j]);
            }
        }
    }
    ((float4*)out)[t]                   = make_float4(opx[0], opx[1], opx[2], opx[3]);
    ((float4*)(out + NUM_NODES))[t]     = make_float4(opy[0], opy[1], opy[2], opy[3]);
    ((float4*)(out + 2 * NUM_NODES))[t] = make_float4(nx[0], nx[1], nx[2], nx[3]);
    ((float4*)(out + 3 * NUM_NODES))[t] = make_float4(ny[0], ny[1], ny[2], ny[3]);
}

// ---------------------------------------------------------------- launch
extern "C" void kernel_launch(void* const* d_in, const int* in_sizes, int n_in,
                              void* d_out, int out_size, void* d_ws, size_t ws_size,
                              hipStream_t stream) {
    const float* pos       = (const float*)d_in[0];
    const float* node_sx   = (const float*)d_in[1];
    const float* node_sy   = (const float*)d_in[2];
    // d_in[3] pin_offset_x, d_in[4] pin_offset_y, d_in[5] target_density: unused
    const float* route_map = (const float*)d_in[6];
    const float* pin_map   = (const float*)d_in[7];
    float* out = (float*)d_out;

    char*   ws    = (char*)d_ws;
    Quad*   qmap  = (Quad*)ws;                                  // 4 MB
    float*  inc   = (float*)(ws + sizeof(Quad) * NBX * NBY);    // 4 MB
    float4* part4 = (float4*)((char*)inc + sizeof(float) * NUM_MOVABLE);
    float*  pf    = (float*)(part4 + P1_BLOCKS);

    hipLaunchKernelGGL(prep_kernel, dim3(PREP_BLOCKS), dim3(THREADS), 0, stream,
                       route_map, pin_map, node_sx, node_sy, qmap, pf);
    hipLaunchKernelGGL(pass1_kernel, dim3(P1_BLOCKS), dim3(THREADS), 0, stream,
                       pos, node_sx, node_sy, qmap, inc, part4);
    hipLaunchKernelGGL(apply_kernel, dim3(AP_BLOCKS), dim3(THREADS), 0, stream,
                       pos, node_sx, node_sy, inc, part4, pf, out);
}